// Round 9
// baseline (167.549 us; speedup 1.0000x reference)
//
#include <hip/hip_runtime.h>

// Banded stereo cost volume via MFMA, all 3 scales in ONE launch.
// cost[j,h,x] = sum_c L[c,h,x]*R[c,h,x-j], 0 if x<j. C=32.
//
// Round-13: barrier-free per-wave epilogue + occupancy 3.
// r12 (=r11) fixed the acc scratch spill (dur_us 220->166, kernel ~51us)
// but kept a block-cooperative epilogue: 24 __syncthreads at 2 blocks/CU
// (nothing to hide the stalls), an 8-way-conflicted gather (n*16+m layout
// -> banks 16(n&1)+m, m in {i,i+4,i+8,i+12} = 8 banks / 64 lanes, ~10us
// of LDS pipe at scale0), and 8 waves/CU to hide ~900cy staging latency.
// This round:
//  - per-wave private epilogue window (4.25 KB/wave): deposits+gathers are
//    wave-local, in-order DS semantics = the only sync. ZERO barriers after
//    the staging one. (r5 tried this but its perf loss was the acc spill,
//    not the store granularity: 8-lane x 16B = 128B aligned full L2 lines.)
//  - tile rows padded to 17 words (n*17+m): gather bank = (17n+m)%32,
//    16 distinct residues -> ~conflict-free. Deposit = b128 stride-17.
//  - LDS 52.0 KB total (St 35840 + Ep 17408) + launch_bounds(256,3)
//    -> 3 blocks/CU, 12 waves, +50% latency hiding. VGPR cap 170 vs ~150
//    needed; spill tripwire = dur_us regression -> revert to (256,2).
// Core (verified r5/r6/r8, absmax 0.25): per h, C[x,x'] = sum_c L[c,x]*
// R[c,x'] on band 0<=x-x'<=D-1; K=32 = ONE v_mfma_f32_16x16x32_f16/tile.
// R staged zero-padded for x'<0 -> band zeros fall out of the matmul.
// Wave w: m-tiles 2w,2w+1; 13 n-tiles each; 26 mfma, 104 acc regs.
// Staging (r8): f16 rows stride 80 B, chunk-XOR (row>>2)&3 swizzle.

#define NBLK_TOTAL 1344
#define SRB 80          // staging row stride in BYTES
#define EPT 272         // epilogue tile stride in floats (16 rows x 17)
#define EPW 1088        // epilogue floats per wave (4 tiles)

typedef float vf4 __attribute__((ext_vector_type(4)));
typedef float f32x4 __attribute__((ext_vector_type(4)));
typedef _Float16 h4 __attribute__((ext_vector_type(4)));
typedef _Float16 h8 __attribute__((ext_vector_type(8)));

template<int DG>
__device__ __forceinline__ void epilogue_w(const f32x4 (&acc0)[13], const f32x4 (&acc1)[13],
                                           float* __restrict__ Ew, float* __restrict__ o,
                                           int H, int W, int h, int xw,
                                           int l, int lm, int kg)
{
    // Tile (mt, slot) at (mt*2+slot)*EPT; word = n*17 + m.
    // jg consumes rel 12-jg (slot jg&1, deposited at jg-1) and 11-jg
    // (slot (jg+1)&1, deposited this step). All indices static after unroll.
    const int jo0 = l >> 3;          // 0..7
    const int xbl = (l & 7) * 4;     // 0..28
    const int mt  = xbl >> 4;        // 0..1
    const int mb  = xbl & 15;
    const int dep = lm * 17 + 4 * kg;

    #pragma unroll
    for (int jg = 0; jg < DG; ++jg) {
        if (jg == 0) {               // rel 12 -> slot 0
            *(f32x4*)&Ew[(0 * 2 + 0) * EPT + dep] = acc0[12];
            *(f32x4*)&Ew[(1 * 2 + 0) * EPT + dep] = acc1[12];
        }
        {                            // rel 11-jg -> slot (11-jg)&1
            const int slot = (11 - jg) & 1;
            *(f32x4*)&Ew[(0 * 2 + slot) * EPT + dep] = acc0[11 - jg];
            *(f32x4*)&Ew[(1 * 2 + slot) * EPT + dep] = acc1[11 - jg];
        }
        const int s12 = jg & 1;      // slot of rel 12-jg
        const int s11 = s12 ^ 1;     // slot of rel 11-jg
        #pragma unroll
        for (int r = 0; r < 2; ++r) {
            int jo = 8 * r + jo0;
            int j  = 16 * jg + jo;
            vf4 v;
            #pragma unroll
            for (int i = 0; i < 4; ++i) {
                int m = mb + i;                    // <= 15
                int slot = (m >= jo) ? s12 : s11;
                int n = (m - jo) & 15;
                v[i] = Ew[(mt * 2 + slot) * EPT + n * 17 + m];
            }
            // 8 lanes x 16B = 128-B aligned full L2 line per j-row.
            float* p = o + ((size_t)j * H + h) * W + xw + xbl;
            __builtin_nontemporal_store(v, (vf4*)p);
        }
    }
}

__global__ __launch_bounds__(256, 3)
void cost_volume_fused(const float* __restrict__ L0, const float* __restrict__ R0,
                       const float* __restrict__ L1, const float* __restrict__ R1,
                       const float* __restrict__ L2, const float* __restrict__ R2,
                       float* __restrict__ out)
{
    // Staging: 448 rows (L: 0..127 = x-x0; R: 128..447 = x'-(x0-192)),
    // 64 B payload, 80 B stride. 35 KB.
    __shared__ __align__(16) char St[448 * SRB];
    // Epilogue: 4 waves x 1088 floats (private windows). 17 KB.
    __shared__ __align__(16) float Ep[4 * EPW];

    // XCD-chunked bijective swizzle: 1344 = 8 * 168.
    const int id = (blockIdx.x & 7) * 168 + (blockIdx.x >> 3);

    const float* L; const float* R; float* o;
    int H, W, D, bx, h;
    if (id < 1024) {            // scale 0: H=256 W=512 D=192
        L = L0; R = R0; o = out;
        H = 256; W = 512; D = 192;
        bx = id & 3; h = id >> 2;
    } else if (id < 1280) {     // scale 1: H=128 W=256 D=96
        int r = id - 1024;
        L = L1; R = R1; o = out + (size_t)192 * 256 * 512;
        H = 128; W = 256; D = 96;
        bx = r & 1; h = r >> 1;
    } else {                    // scale 2: H=64 W=128 D=48
        int r = id - 1280;
        L = L2; R = R2; o = out + (size_t)192 * 256 * 512 + (size_t)96 * 128 * 256;
        H = 64; W = 128; D = 48;
        bx = 0; h = r;
    }

    const int x0 = bx * 128;
    const int t  = threadIdx.x;
    const int l  = t & 63;
    const int w_ = t >> 6;

    const size_t HW = (size_t)H * W;
    const float* Lb = L + (size_t)h * W;
    const float* Rb = R + (size_t)h * W;

    char* Sb = (char*)St;

    // ---- stage L: 256 items = (c4, x4); 4x4 reg transpose, f32 -> f16 ----
    {
        const int c0 = (t >> 5) * 4;
        const int x4 = t & 31;
        const float* gp = Lb + (size_t)c0 * HW + x0 + 4 * x4;
        vf4 v0 = *(const vf4*)(gp);
        vf4 v1 = *(const vf4*)(gp + HW);
        vf4 v2 = *(const vf4*)(gp + 2 * HW);
        vf4 v3 = *(const vf4*)(gp + 3 * HW);
        const int chk = (((c0 >> 3) ^ (x4 & 3)) << 4) | ((c0 & 7) << 1);
        #pragma unroll
        for (int xi = 0; xi < 4; ++xi) {
            int row = 4 * x4 + xi;            // (row>>2)&3 == x4&3
            h4 hv = { (_Float16)v0[xi], (_Float16)v1[xi],
                      (_Float16)v2[xi], (_Float16)v3[xi] };
            *(h4*)(Sb + row * SRB + chk) = hv;
        }
    }
    // ---- stage R: 640 items; x' = x0-192+4*x4; x'<0 rows = 0 ----
    #pragma unroll
    for (int k = 0; k < 3; ++k) {
        int idm = t + k * 256;
        if (idm < 640) {
            int c0 = (idm / 80) * 4;
            int x4 = idm - (idm / 80) * 80;
            int g = x0 - 192 + 4 * x4;
            vf4 v0 = (vf4)(0.f), v1 = (vf4)(0.f), v2 = (vf4)(0.f), v3 = (vf4)(0.f);
            if (g >= 0) {   // g+3 <= x0+127 <= W-1 always
                const float* gp = Rb + (size_t)c0 * HW + g;
                v0 = *(const vf4*)(gp);
                v1 = *(const vf4*)(gp + HW);
                v2 = *(const vf4*)(gp + 2 * HW);
                v3 = *(const vf4*)(gp + 3 * HW);
            }
            const int chk = (((c0 >> 3) ^ (x4 & 3)) << 4) | ((c0 & 7) << 1);
            #pragma unroll
            for (int xi = 0; xi < 4; ++xi) {
                int row = 128 + 4 * x4 + xi;   // (row>>2)&3 == x4&3 (128%4==0)
                h4 hv = { (_Float16)v0[xi], (_Float16)v1[xi],
                          (_Float16)v2[xi], (_Float16)v3[xi] };
                *(h4*)(Sb + row * SRB + chk) = hv;
            }
        }
    }
    __syncthreads();   // the ONLY barrier in the kernel

    // ---- MFMA: wave w -> m-tiles q0=2w, q0+1; n-tiles q..q+12 each ----
    const int lm = l & 15;
    const int kg = l >> 4;
    const int q0 = 2 * w_;
    const int rsw = (lm >> 2) & 3;        // (row>>2)&3 for rows 16q+lm

    f32x4 acc0[13], acc1[13];
    #pragma unroll
    for (int i = 0; i < 13; ++i) { acc0[i] = (f32x4)(0.f); acc1[i] = (f32x4)(0.f); }

    const int rowA0 = 16 * q0 + lm;
    const int rowA1 = rowA0 + 16;
    h8 a0 = *(const h8*)(Sb + rowA0 * SRB + ((kg ^ rsw) << 4));
    h8 a1 = *(const h8*)(Sb + rowA1 * SRB + ((kg ^ rsw) << 4));

    #pragma unroll
    for (int nt = 0; nt <= 13; ++nt) {
        int rowB = 128 + 16 * (q0 + nt) + lm;
        h8 b = *(const h8*)(Sb + rowB * SRB + ((kg ^ rsw) << 4));
        if (nt <= 12)
            acc0[nt] = __builtin_amdgcn_mfma_f32_16x16x32_f16(a0, b, acc0[nt], 0, 0, 0);
        if (nt >= 1)
            acc1[nt - 1] = __builtin_amdgcn_mfma_f32_16x16x32_f16(a1, b, acc1[nt - 1], 0, 0, 0);
    }

    // ---- epilogue: per-wave private window, no barriers, static DG ----
    float* Ew = Ep + w_ * EPW;
    const int xw = x0 + 32 * w_;
    if (D == 192)      epilogue_w<12>(acc0, acc1, Ew, o, H, W, h, xw, l, lm, kg);
    else if (D == 96)  epilogue_w<6>(acc0, acc1, Ew, o, H, W, h, xw, l, lm, kg);
    else               epilogue_w<3>(acc0, acc1, Ew, o, H, W, h, xw, l, lm, kg);
}

extern "C" void kernel_launch(void* const* d_in, const int* in_sizes, int n_in,
                              void* d_out, int out_size, void* d_ws, size_t ws_size,
                              hipStream_t stream)
{
    const float* L0 = (const float*)d_in[0];
    const float* R0 = (const float*)d_in[1];
    const float* L1 = (const float*)d_in[2];
    const float* R1 = (const float*)d_in[3];
    const float* L2 = (const float*)d_in[4];
    const float* R2 = (const float*)d_in[5];
    float* out = (float*)d_out;

    cost_volume_fused<<<dim3(NBLK_TOTAL), dim3(256), 0, stream>>>(
        L0, R0, L1, R1, L2, R2, out);
}

// Round 10
// 163.262 us; speedup vs baseline: 1.0263x; 1.0263x over previous
//
#include <hip/hip_runtime.h>

// Banded stereo cost volume via MFMA, all 3 scales in ONE launch.
// cost[j,h,x] = sum_c L[c,h,x]*R[c,h,x-j], 0 if x<j. C=32.
//
// Round-14: split D across blocks to halve the accumulator and raise MLP.
// r8/r9 A/B showed epilogue barriers/conflicts and 2->3 blocks/CU are NOT
// the residual (both ~167us); r6-FETCH minus spill ~= 44MB = compulsory, so
// L2 already absorbs R-window overlap. Remaining theory: 104 acc VGPRs cap
// occupancy at 3 waves/SIMD; staging (14 loads/thread before the barrier)
// lacks MLP. This round: each block does a 96-j half (scale0: 2 j-blocks
// per (bx,h)):
//   - acc 13 -> 7 tiles/m-tile = 56 regs (~100 total), launch_bounds(256,4)
//     -> 4 blocks / 16 waves per CU (+33%)
//   - R window 320 -> 224 rows; staged bytes/block 35 -> 27.5 KB
//   - epilogue buffer UNIONED into St (dead after frag reads; one extra
//     barrier) -> LDS 27.5 KB total
//   - grid 1344 -> 2368 = 8*296 (bijective XCD swizzle kept; j-halves of
//     one (bx,h) adjacent -> same XCD, overlapping R windows L2-shared)
// All index machinery identical to r9 with diag const 12 -> 6 (same
// parity -> slot logic unchanged). Core verified r5/r6/r8/r9 (absmax .25).

#define NBLK_TOTAL 2368
#define SRB 80          // staging row stride in BYTES
#define NRW 352         // staged rows: L 128 (x-x0) + R 224 (x'-GB)
#define EPT 272         // epilogue tile stride in floats (16 rows x 17)
#define EPW 1088        // epilogue floats per wave (4 tiles)

typedef float vf4 __attribute__((ext_vector_type(4)));
typedef float f32x4 __attribute__((ext_vector_type(4)));
typedef _Float16 h4 __attribute__((ext_vector_type(4)));
typedef _Float16 h8 __attribute__((ext_vector_type(8)));

template<int DG>
__device__ __forceinline__ void epilogue_w(const f32x4 (&acc0)[7], const f32x4 (&acc1)[7],
                                           float* __restrict__ Ew, float* __restrict__ o,
                                           int H, int W, int h, int j0, int xw,
                                           int l, int lm, int kg)
{
    // Tile (mt, slot) at (mt*2+slot)*EPT; word = n*17 + m (17 odd -> ~no
    // bank conflicts). jg consumes rel 6-jg (slot jg&1, deposited at jg-1)
    // and 5-jg (slot (jg+1)&1, deposited this step). All static post-unroll.
    const int jo0 = l >> 3;          // 0..7
    const int xbl = (l & 7) * 4;     // 0..28
    const int mt  = xbl >> 4;        // 0..1
    const int mb  = xbl & 15;
    const int dep = lm * 17 + 4 * kg;

    #pragma unroll
    for (int jg = 0; jg < DG; ++jg) {
        if (jg == 0) {               // rel 6 -> slot 0
            *(f32x4*)&Ew[(0 * 2 + 0) * EPT + dep] = acc0[6];
            *(f32x4*)&Ew[(1 * 2 + 0) * EPT + dep] = acc1[6];
        }
        {                            // rel 5-jg -> slot (5-jg)&1
            const int slot = (5 - jg) & 1;
            *(f32x4*)&Ew[(0 * 2 + slot) * EPT + dep] = acc0[5 - jg];
            *(f32x4*)&Ew[(1 * 2 + slot) * EPT + dep] = acc1[5 - jg];
        }
        const int s6 = jg & 1;       // slot of rel 6-jg
        const int s5 = s6 ^ 1;       // slot of rel 5-jg
        #pragma unroll
        for (int r = 0; r < 2; ++r) {
            int jo = 8 * r + jo0;
            int j  = j0 + 16 * jg + jo;
            vf4 v;
            #pragma unroll
            for (int i = 0; i < 4; ++i) {
                int m = mb + i;                    // <= 15
                int slot = (m >= jo) ? s6 : s5;
                int n = (m - jo) & 15;
                v[i] = Ew[(mt * 2 + slot) * EPT + n * 17 + m];
            }
            // 8 lanes x 16B = 128-B aligned full line per j-row.
            float* p = o + ((size_t)j * H + h) * W + xw + xbl;
            __builtin_nontemporal_store(v, (vf4*)p);
        }
    }
}

__global__ __launch_bounds__(256, 4)
void cost_volume_fused(const float* __restrict__ L0, const float* __restrict__ R0,
                       const float* __restrict__ L1, const float* __restrict__ R1,
                       const float* __restrict__ L2, const float* __restrict__ R2,
                       float* __restrict__ out)
{
    // Staging: 352 rows x 80 B = 27.5 KB. Epilogue windows (17 KB) are
    // UNIONED into this space (St dead after frag reads; barrier between).
    __shared__ __align__(16) char St[NRW * SRB];

    // XCD-chunked bijective swizzle: 2368 = 8 * 296.
    const int id = (blockIdx.x & 7) * 296 + (blockIdx.x >> 3);

    const float* L; const float* R; float* o;
    int H, W, D, bx, h, j0, DG;
    if (id < 2048) {            // scale 0: H=256 W=512 D=192; 2 j-halves
        L = L0; R = R0; o = out;
        H = 256; W = 512; D = 192;
        j0 = (id & 1) * 96; bx = (id >> 1) & 3; h = id >> 3; DG = 6;
    } else if (id < 2304) {     // scale 1: H=128 W=256 D=96
        int r = id - 2048;
        L = L1; R = R1; o = out + (size_t)192 * 256 * 512;
        H = 128; W = 256; D = 96;
        j0 = 0; bx = r & 1; h = r >> 1; DG = 6;
    } else {                    // scale 2: H=64 W=128 D=48
        int r = id - 2304;
        L = L2; R = R2; o = out + (size_t)192 * 256 * 512 + (size_t)96 * 128 * 256;
        H = 64; W = 128; D = 48;
        j0 = 0; bx = 0; h = r; DG = 3;
    }

    const int x0 = bx * 128;
    const int GB = x0 - j0 - 96;      // x' of R row 0 (may be <0 -> zero rows)
    const int t  = threadIdx.x;
    const int l  = t & 63;
    const int w_ = t >> 6;

    const size_t HW = (size_t)H * W;
    const float* Lb = L + (size_t)h * W;
    const float* Rb = R + (size_t)h * W;

    char* Sb = (char*)St;

    // ---- stage L: 256 items = (c4, x4); 4x4 reg transpose, f32 -> f16 ----
    {
        const int c0 = (t >> 5) * 4;
        const int x4 = t & 31;
        const float* gp = Lb + (size_t)c0 * HW + x0 + 4 * x4;
        vf4 v0 = *(const vf4*)(gp);
        vf4 v1 = *(const vf4*)(gp + HW);
        vf4 v2 = *(const vf4*)(gp + 2 * HW);
        vf4 v3 = *(const vf4*)(gp + 3 * HW);
        const int chk = (((c0 >> 3) ^ (x4 & 3)) << 4) | ((c0 & 7) << 1);
        #pragma unroll
        for (int xi = 0; xi < 4; ++xi) {
            int row = 4 * x4 + xi;            // (row>>2)&3 == x4&3
            h4 hv = { (_Float16)v0[xi], (_Float16)v1[xi],
                      (_Float16)v2[xi], (_Float16)v3[xi] };
            *(h4*)(Sb + row * SRB + chk) = hv;
        }
    }
    // ---- stage R: 448 items = 8 c4-groups x 56 x4; x' = GB + 4*x4 ----
    #pragma unroll
    for (int k = 0; k < 2; ++k) {
        int idm = t + k * 256;
        if (idm < 448) {
            int c0 = (idm / 56) * 4;
            int x4 = idm - (idm / 56) * 56;
            int g = GB + 4 * x4;
            vf4 v0 = (vf4)(0.f), v1 = (vf4)(0.f), v2 = (vf4)(0.f), v3 = (vf4)(0.f);
            if (g >= 0) {   // g+3 <= W-1 by construction at every scale
                const float* gp = Rb + (size_t)c0 * HW + g;
                v0 = *(const vf4*)(gp);
                v1 = *(const vf4*)(gp + HW);
                v2 = *(const vf4*)(gp + 2 * HW);
                v3 = *(const vf4*)(gp + 3 * HW);
            }
            const int chk = (((c0 >> 3) ^ (x4 & 3)) << 4) | ((c0 & 7) << 1);
            #pragma unroll
            for (int xi = 0; xi < 4; ++xi) {
                int row = 128 + 4 * x4 + xi;   // (row>>2)&3 == x4&3 (128%16==0)
                h4 hv = { (_Float16)v0[xi], (_Float16)v1[xi],
                          (_Float16)v2[xi], (_Float16)v3[xi] };
                *(h4*)(Sb + row * SRB + chk) = hv;
            }
        }
    }
    __syncthreads();

    // ---- MFMA: wave w -> m-tiles q0=2w, q0+1; 7 n-tiles (rel 0..6) ----
    const int lm = l & 15;
    const int kg = l >> 4;
    const int q0 = 2 * w_;
    const int rsw = (lm >> 2) & 3;        // (row>>2)&3 for rows 16q+lm

    f32x4 acc0[7], acc1[7];
    #pragma unroll
    for (int i = 0; i < 7; ++i) { acc0[i] = (f32x4)(0.f); acc1[i] = (f32x4)(0.f); }

    const int rowA0 = 16 * q0 + lm;
    const int rowA1 = rowA0 + 16;
    h8 a0 = *(const h8*)(Sb + rowA0 * SRB + ((kg ^ rsw) << 4));
    h8 a1 = *(const h8*)(Sb + rowA1 * SRB + ((kg ^ rsw) << 4));

    #pragma unroll
    for (int nt = 0; nt <= 7; ++nt) {
        int rowB = 128 + 16 * (q0 + nt) + lm;     // max 128+16*13+15 = 351
        h8 b = *(const h8*)(Sb + rowB * SRB + ((kg ^ rsw) << 4));
        if (nt <= 6)
            acc0[nt] = __builtin_amdgcn_mfma_f32_16x16x32_f16(a0, b, acc0[nt], 0, 0, 0);
        if (nt >= 1)
            acc1[nt - 1] = __builtin_amdgcn_mfma_f32_16x16x32_f16(a1, b, acc1[nt - 1], 0, 0, 0);
    }

    __syncthreads();   // all frag reads done -> St reusable as epilogue space

    // ---- epilogue: per-wave window in unioned St, no further barriers ----
    float* Ew = (float*)St + w_ * EPW;
    const int xw = x0 + 32 * w_;
    if (DG == 6) epilogue_w<6>(acc0, acc1, Ew, o, H, W, h, j0, xw, l, lm, kg);
    else         epilogue_w<3>(acc0, acc1, Ew, o, H, W, h, j0, xw, l, lm, kg);
}

extern "C" void kernel_launch(void* const* d_in, const int* in_sizes, int n_in,
                              void* d_out, int out_size, void* d_ws, size_t ws_size,
                              hipStream_t stream)
{
    const float* L0 = (const float*)d_in[0];
    const float* R0 = (const float*)d_in[1];
    const float* L1 = (const float*)d_in[2];
    const float* R1 = (const float*)d_in[3];
    const float* L2 = (const float*)d_in[4];
    const float* R2 = (const float*)d_in[5];
    float* out = (float*)d_out;

    cost_volume_fused<<<dim3(NBLK_TOTAL), dim3(256), 0, stream>>>(
        L0, R0, L1, R1, L2, R2, out);
}